// Round 4
// baseline (4194.461 us; speedup 1.0000x reference)
//
#include <hip/hip_runtime.h>
#include <hip/hip_bf16.h>
#include <stdint.h>

typedef __bf16 bf16;
typedef __bf16 v8bf __attribute__((ext_vector_type(8)));
typedef float  v4f  __attribute__((ext_vector_type(4)));

#define MFMA_BF16(a,b,c) __builtin_amdgcn_mfma_f32_16x16x32_bf16((a),(b),(c),0,0,0)

__device__ __forceinline__ float wred_sum(float v) {
#pragma unroll
  for (int o = 32; o; o >>= 1) v += __shfl_xor(v, o);
  return v;
}
__device__ __forceinline__ float wred_max(float v) {
#pragma unroll
  for (int o = 32; o; o >>= 1) v = fmaxf(v, __shfl_xor(v, o));
  return v;
}

// ---------------- dtype sniffer ----------------
// Examines first 2048 u16 of x. If the buffer is bf16(N(0,1)-ish), ~100% of
// halfwords have a sane bf16 exponent. If it is fp32, even halfwords are fp32
// mantissa bits -> bf16-exponent field ~uniform -> only ~58% sane overall.
__global__ void k_sniff(const unsigned short* __restrict__ x, int* __restrict__ flag) {
  int cnt = 0;
  for (int i = threadIdx.x; i < 2048; i += 64) {
    const unsigned short u = x[i];
    const int e = (u >> 7) & 0xFF;
    if (u == 0 || (e >= 100 && e <= 140)) cnt++;
  }
#pragma unroll
  for (int o = 32; o; o >>= 1) cnt += __shfl_xor(cnt, o);
  if (threadIdx.x == 0) flag[0] = (cnt >= 1844) ? 0 : 1;  // 0 = bf16, 1 = f32
}

// ---------------- small utility kernels ----------------

__global__ void k_zero(float* p, int n) {
  int i = threadIdx.x;
  if (i < n) p[i] = 0.0f;
}

__global__ __launch_bounds__(256) void k_abssum(const void* __restrict__ w, int n,
                                                const int* __restrict__ flag,
                                                float* __restrict__ out) {
  const int tid = threadIdx.x;
  const int f32 = flag[0];
  __shared__ float sred[4];
  float s = 0.0f;
  if (f32) {
    const float4* p = (const float4*)w;
    for (int i = (blockIdx.x * 256 + tid) * 2; i * 4 < n; i += gridDim.x * 512) {
      float4 a = p[i], b = p[i + 1];
      s += fabsf(a.x) + fabsf(a.y) + fabsf(a.z) + fabsf(a.w) +
           fabsf(b.x) + fabsf(b.y) + fabsf(b.z) + fabsf(b.w);
    }
  } else {
    const bf16* p = (const bf16*)w;
    for (int i = (blockIdx.x * 256 + tid) * 8; i < n; i += gridDim.x * 2048) {
      v8bf v = *(const v8bf*)(p + i);
#pragma unroll
      for (int j = 0; j < 8; j++) s += fabsf((float)v[j]);
    }
  }
  s = wred_sum(s);
  if ((tid & 63) == 0) sred[tid >> 6] = s;
  __syncthreads();
  if (tid == 0) atomicAdd(out, sred[0] + sred[1] + sred[2] + sred[3]);
}

__global__ __launch_bounds__(256) void k_wquant(const void* __restrict__ w, bf16* __restrict__ o,
                                                const float* __restrict__ sum, float invn,
                                                const int* __restrict__ flag) {
  const int gid = blockIdx.x * 256 + threadIdx.x;
  const int i = gid * 8;
  const float ws = 1.0f / fmaxf(sum[0] * invn, 1e-5f);
  const int f32 = flag[0];
  float v[8];
  if (f32) {
    float4 a = ((const float4*)w)[gid * 2];
    float4 b = ((const float4*)w)[gid * 2 + 1];
    v[0] = a.x; v[1] = a.y; v[2] = a.z; v[3] = a.w;
    v[4] = b.x; v[5] = b.y; v[6] = b.z; v[7] = b.w;
  } else {
    v8bf t = *(const v8bf*)((const bf16*)w + i);
#pragma unroll
    for (int j = 0; j < 8; j++) v[j] = (float)t[j];
  }
  v8bf r;
#pragma unroll
  for (int j = 0; j < 8; j++) {
    float t = rintf(v[j] * ws);
    r[j] = (bf16)fminf(fmaxf(t, -1.0f), 1.0f);
  }
  *(v8bf*)(o + i) = r;
}

// LayerNorm + per-row absmax quantize (integer-valued bf16 out).
// XINT=true: x is an internal fp32 buffer. Otherwise x dtype follows flag.
// g/b always follow flag.
template <bool XINT>
__global__ __launch_bounds__(256) void k_lnq(const void* __restrict__ x, const void* __restrict__ g,
                                             const void* __restrict__ b, bf16* __restrict__ q,
                                             float* __restrict__ sc, const int* __restrict__ flag) {
  const int row = blockIdx.x, tid = threadIdx.x;
  const int f32 = flag[0];
  __shared__ float sred[4];
  float v[8];
#pragma unroll
  for (int i = 0; i < 8; i++) {
    const size_t idx = (size_t)row * 2048 + tid + 256 * i;
    if (XINT)      v[i] = ((const float*)x)[idx];
    else if (f32)  v[i] = ((const float*)x)[idx];
    else           v[i] = (float)((const bf16*)x)[idx];
  }
  float s = 0.0f;
#pragma unroll
  for (int i = 0; i < 8; i++) s += v[i];
  s = wred_sum(s);
  if ((tid & 63) == 0) sred[tid >> 6] = s;
  __syncthreads();
  const float mean = (sred[0] + sred[1] + sred[2] + sred[3]) * (1.0f / 2048.0f);
  __syncthreads();
  float vs = 0.0f;
#pragma unroll
  for (int i = 0; i < 8; i++) { float d = v[i] - mean; vs += d * d; }
  vs = wred_sum(vs);
  if ((tid & 63) == 0) sred[tid >> 6] = vs;
  __syncthreads();
  const float rstd = rsqrtf((sred[0] + sred[1] + sred[2] + sred[3]) * (1.0f / 2048.0f) + 1e-6f);
  __syncthreads();
  float hq[8];
  float am = 0.0f;
#pragma unroll
  for (int i = 0; i < 8; i++) {
    const int c = tid + 256 * i;
    const float gv = f32 ? ((const float*)g)[c] : (float)((const bf16*)g)[c];
    const float bv = f32 ? ((const float*)b)[c] : (float)((const bf16*)b)[c];
    hq[i] = (v[i] - mean) * rstd * gv + bv;
    am = fmaxf(am, fabsf(hq[i]));
  }
  am = wred_max(am);
  if ((tid & 63) == 0) sred[tid >> 6] = am;
  __syncthreads();
  am = fmaxf(fmaxf(sred[0], sred[1]), fmaxf(sred[2], sred[3]));
  const float cl = fmaxf(am, 1e-5f);
  const float s127 = 127.0f / cl;
#pragma unroll
  for (int i = 0; i < 8; i++) {
    float r = rintf(hq[i] * s127);
    r = fminf(fmaxf(r, -128.0f), 127.0f);
    q[(size_t)row * 2048 + tid + 256 * i] = (bf16)r;
  }
  if (tid == 0) sc[row] = cl * (1.0f / 127.0f);
}

// plain per-row absmax quantize; safe in-place (reads before writes, internal bf16)
template <int IT>
__global__ __launch_bounds__(256) void k_rowq(const bf16* __restrict__ in, bf16* __restrict__ q,
                                              float* __restrict__ sc) {
  const int row = blockIdx.x, tid = threadIdx.x;
  const int C = IT * 256;
  __shared__ float sred[4];
  const bf16* xr = in + (size_t)row * C;
  float v[IT];
  float am = 0.0f;
#pragma unroll
  for (int i = 0; i < IT; i++) {
    v[i] = (float)xr[tid + 256 * i];
    am = fmaxf(am, fabsf(v[i]));
  }
  am = wred_max(am);
  if ((tid & 63) == 0) sred[tid >> 6] = am;
  __syncthreads();
  am = fmaxf(fmaxf(sred[0], sred[1]), fmaxf(sred[2], sred[3]));
  const float cl = fmaxf(am, 1e-5f);
  const float s127 = 127.0f / cl;
#pragma unroll
  for (int i = 0; i < IT; i++) {
    float r = rintf(v[i] * s127);
    r = fminf(fmaxf(r, -128.0f), 127.0f);
    q[(size_t)row * C + tid + 256 * i] = (bf16)r;
  }
  if (tid == 0) sc[row] = cl * (1.0f / 127.0f);
}

// ---------------- GEMM: C[t,n] = sA[t]*cw * sum_k A[t,k]*B[n,k] ----------------
// Explicit staging (m92-style). A,B internal bf16 (integer-valued).
// EPI 0: out bf16 = val                        (QKV projections)
// EPI 1: out f32  = resid(ext, per flag) + val (wo projection -> x1)
// EPI 2: out bf16 = relu(val)^2                (w1 -> F)
// EPI 3: out(ext, per flag) = f32 resid + val  (w2 -> final output)
template <int EPI>
__global__ __launch_bounds__(256) void k_gemm(const bf16* __restrict__ A, const bf16* __restrict__ B,
                                              const float* __restrict__ sA,
                                              const float* __restrict__ wsum, float winv,
                                              const void* __restrict__ resid, void* __restrict__ out,
                                              int M, int N, int K, const int* __restrict__ flag) {
  __shared__ __align__(16) bf16 As[128 * 32];
  __shared__ __align__(16) bf16 Bs[128 * 32];
  const int tid = threadIdx.x;
  const int lane = tid & 63;
  const int ml = lane & 15;
  const int q4 = lane >> 4;
  const int wid = tid >> 6;
  const int wM = wid >> 1;
  const int wN = wid & 1;
  const int m0 = blockIdx.y * 128;
  const int n0 = blockIdx.x * 128;

  const int r0 = tid >> 2;
  const int c0 = (tid & 3) * 8;
  const bf16* Ag0 = A + (size_t)(m0 + r0) * K + c0;
  const bf16* Ag1 = Ag0 + (size_t)64 * K;
  const bf16* Bg0 = B + (size_t)(n0 + r0) * K + c0;
  const bf16* Bg1 = Bg0 + (size_t)64 * K;

  v4f acc[4][4] = {};

  for (int k0 = 0; k0 < K; k0 += 32) {
    v8bf a0 = *(const v8bf*)(Ag0 + k0);
    v8bf a1 = *(const v8bf*)(Ag1 + k0);
    v8bf b0 = *(const v8bf*)(Bg0 + k0);
    v8bf b1 = *(const v8bf*)(Bg1 + k0);
    __syncthreads();
    *(v8bf*)&As[tid * 8] = a0;
    *(v8bf*)&As[2048 + tid * 8] = a1;
    *(v8bf*)&Bs[tid * 8] = b0;
    *(v8bf*)&Bs[2048 + tid * 8] = b1;
    __syncthreads();
    v8bf af[4], bfr[4];
#pragma unroll
    for (int i = 0; i < 4; i++) af[i] = *(const v8bf*)&As[(wM * 64 + i * 16 + ml) * 32 + q4 * 8];
#pragma unroll
    for (int j = 0; j < 4; j++) bfr[j] = *(const v8bf*)&Bs[(wN * 64 + j * 16 + ml) * 32 + q4 * 8];
#pragma unroll
    for (int i = 0; i < 4; i++)
#pragma unroll
      for (int j = 0; j < 4; j++) acc[i][j] = MFMA_BF16(af[i], bfr[j], acc[i][j]);
  }

  const float cw = fmaxf(wsum[0] * winv, 1e-5f);
  const int f32 = flag[0];
#pragma unroll
  for (int i = 0; i < 4; i++) {
#pragma unroll
    for (int r = 0; r < 4; r++) {
      const int row = m0 + wM * 64 + i * 16 + q4 * 4 + r;
      const float sa = sA[row] * cw;
#pragma unroll
      for (int j = 0; j < 4; j++) {
        const int col = n0 + wN * 64 + j * 16 + ml;
        const float val = acc[i][j][r] * sa;
        const size_t idx = (size_t)row * N + col;
        if (EPI == 0) {
          ((bf16*)out)[idx] = (bf16)val;
        } else if (EPI == 1) {
          const float rv = f32 ? ((const float*)resid)[idx] : (float)((const bf16*)resid)[idx];
          ((float*)out)[idx] = rv + val;
        } else if (EPI == 2) {
          float u = fmaxf(val, 0.0f);
          ((bf16*)out)[idx] = (bf16)(u * u);
        } else {
          const float ov = ((const float*)resid)[idx] + val;
          if (f32) ((float*)out)[idx] = ov;
          else     ((bf16*)out)[idx] = (bf16)ov;
        }
      }
    }
  }
}

// ---------------- simple VALU flash attention (causal, GQA, D=64) ----------------
__global__ __launch_bounds__(256) void k_attn_simple(const bf16* __restrict__ Q,
                                                     const bf16* __restrict__ K,
                                                     const bf16* __restrict__ V,
                                                     bf16* __restrict__ O) {
  const int q = blockIdx.x;
  const int h = blockIdx.y;
  const int kvh = h >> 2;
  const int tid = threadIdx.x;
  __shared__ float qs[64];
  __shared__ float Sc[2048];
  __shared__ float red[4];
  __shared__ float part[4][64];

  if (tid < 64) qs[tid] = (float)Q[(size_t)q * 2048 + h * 64 + tid];
  __syncthreads();

  float lm = -1e30f;
  for (int j = tid; j < 2048; j += 256) {
    float s = -1e30f;
    if (j <= q) {
      const v8bf* kr = (const v8bf*)(K + (size_t)j * 512 + kvh * 64);
      float acc = 0.0f;
#pragma unroll
      for (int c = 0; c < 8; c++) {
        v8bf kv8 = kr[c];
#pragma unroll
        for (int u = 0; u < 8; u++) acc += qs[c * 8 + u] * (float)kv8[u];
      }
      s = acc * 0.125f;
    }
    Sc[j] = s;
    lm = fmaxf(lm, s);
  }
  lm = wred_max(lm);
  if ((tid & 63) == 0) red[tid >> 6] = lm;
  __syncthreads();
  const float M = fmaxf(fmaxf(red[0], red[1]), fmaxf(red[2], red[3]));
  __syncthreads();

  float ls = 0.0f;
  for (int j = tid; j < 2048; j += 256) {
    float e = (j <= q) ? __expf(Sc[j] - M) : 0.0f;
    Sc[j] = e;
    ls += e;
  }
  ls = wred_sum(ls);
  if ((tid & 63) == 0) red[tid >> 6] = ls;
  __syncthreads();
  const float L = red[0] + red[1] + red[2] + red[3];

  const int d = tid & 63, g = tid >> 6;
  const int jend0 = g * 512 + 512;
  const int jend = (jend0 < q + 1) ? jend0 : (q + 1);
  float acc = 0.0f;
  for (int j = g * 512; j < jend; j++)
    acc += Sc[j] * (float)V[(size_t)j * 512 + kvh * 64 + d];
  part[g][d] = acc;
  __syncthreads();
  if (tid < 64) {
    float o = (part[0][tid] + part[1][tid] + part[2][tid] + part[3][tid]) / L;
    O[(size_t)q * 2048 + h * 64 + tid] = (bf16)o;
  }
}

// ---------------- launcher ----------------
// Workspace (96 MB + 64 KB):
//   scalars: wsum[8]@0, s1@8K, so@16K, s2@24K, sf@32K, flag@40K
//   R0 [ 0,32)MB: w1z ............. then w2z (quant AFTER gemm<2>)
//   R1 [32,64)MB: wqz+0 wkz+8 wvz+10 woz+12, then Fb/fq (in-place rowq)
//   R2 [64,80)MB: Qb+0 Kbuf+8 Vb+10, then x1 (fp32, after attention)
//   R3 [80,88)MB: xq1 -> oq -> xq2
//   R4 [88,96)MB: Ob
extern "C" void kernel_launch(void* const* d_in, const int* in_sizes, int n_in, void* d_out,
                              int out_size, void* d_ws, size_t ws_size, hipStream_t stream) {
  const void* x = d_in[0];
  const void* g1 = d_in[1];
  const void* b1 = d_in[2];
  const void* g2 = d_in[3];
  const void* b2 = d_in[4];
  const void* wq = d_in[5];
  const void* wk = d_in[6];
  const void* wv = d_in[7];
  const void* wo = d_in[8];
  const void* w1 = d_in[9];
  const void* w2 = d_in[10];

  char* ws = (char*)d_ws;
  const size_t MB = 1ull << 20;
  float* wsum = (float*)ws;
  float* s1 = (float*)(ws + 8192);
  float* so = (float*)(ws + 16384);
  float* s2 = (float*)(ws + 24576);
  float* sf = (float*)(ws + 32768);
  int* flag = (int*)(ws + 40960);
  char* big = ws + 65536;

  bf16* w1z = (bf16*)(big);
  bf16* w2z = (bf16*)(big);
  bf16* wqz = (bf16*)(big + 32 * MB);
  bf16* wkz = (bf16*)(big + 40 * MB);
  bf16* wvz = (bf16*)(big + 42 * MB);
  bf16* woz = (bf16*)(big + 44 * MB);
  bf16* Fb  = (bf16*)(big + 32 * MB);
  bf16* fq  = Fb;
  bf16* Qb   = (bf16*)(big + 64 * MB);
  bf16* Kbuf = (bf16*)(big + 72 * MB);
  bf16* Vb   = (bf16*)(big + 74 * MB);
  float* x1  = (float*)(big + 64 * MB);
  bf16* xq1 = (bf16*)(big + 80 * MB);
  bf16* oq  = xq1;
  bf16* xq2 = xq1;
  bf16* Ob  = (bf16*)(big + 88 * MB);

  const float invD2 = 1.0f / 4194304.0f;
  const float invKV = 1.0f / 1048576.0f;
  const float invF = 1.0f / 16777216.0f;

  k_sniff<<<1, 64, 0, stream>>>((const unsigned short*)x, flag);
  k_zero<<<1, 64, 0, stream>>>(wsum, 8);
  k_abssum<<<512, 256, 0, stream>>>(wq, 2048 * 2048, flag, wsum + 0);
  k_abssum<<<512, 256, 0, stream>>>(wk, 512 * 2048, flag, wsum + 1);
  k_abssum<<<512, 256, 0, stream>>>(wv, 512 * 2048, flag, wsum + 2);
  k_abssum<<<512, 256, 0, stream>>>(wo, 2048 * 2048, flag, wsum + 3);
  k_abssum<<<512, 256, 0, stream>>>(w1, 8192 * 2048, flag, wsum + 4);
  k_abssum<<<512, 256, 0, stream>>>(w2, 2048 * 8192, flag, wsum + 5);
  k_wquant<<<2048, 256, 0, stream>>>(wq, wqz, wsum + 0, invD2, flag);
  k_wquant<<<512, 256, 0, stream>>>(wk, wkz, wsum + 1, invKV, flag);
  k_wquant<<<512, 256, 0, stream>>>(wv, wvz, wsum + 2, invKV, flag);
  k_wquant<<<2048, 256, 0, stream>>>(wo, woz, wsum + 3, invD2, flag);
  k_wquant<<<8192, 256, 0, stream>>>(w1, w1z, wsum + 4, invF, flag);

  // attention sublayer
  k_lnq<false><<<2048, 256, 0, stream>>>(x, g1, b1, xq1, s1, flag);
  k_gemm<0><<<dim3(16, 16), 256, 0, stream>>>(xq1, wqz, s1, wsum + 0, invD2, nullptr, Qb, 2048, 2048, 2048, flag);
  k_gemm<0><<<dim3(4, 16), 256, 0, stream>>>(xq1, wkz, s1, wsum + 1, invKV, nullptr, Kbuf, 2048, 512, 2048, flag);
  k_gemm<0><<<dim3(4, 16), 256, 0, stream>>>(xq1, wvz, s1, wsum + 2, invKV, nullptr, Vb, 2048, 512, 2048, flag);
  k_attn_simple<<<dim3(2048, 32), 256, 0, stream>>>(Qb, Kbuf, Vb, Ob);
  k_rowq<8><<<2048, 256, 0, stream>>>(Ob, oq, so);
  k_gemm<1><<<dim3(16, 16), 256, 0, stream>>>(oq, woz, so, wsum + 3, invD2, x, x1, 2048, 2048, 2048, flag);

  // FFN sublayer
  k_lnq<true><<<2048, 256, 0, stream>>>(x1, g2, b2, xq2, s2, flag);
  k_gemm<2><<<dim3(64, 16), 256, 0, stream>>>(xq2, w1z, s2, wsum + 4, invF, nullptr, Fb, 2048, 8192, 2048, flag);
  k_wquant<<<8192, 256, 0, stream>>>(w2, w2z, wsum + 5, invF, flag);
  k_rowq<32><<<2048, 256, 0, stream>>>(Fb, fq, sf);
  k_gemm<3><<<dim3(16, 16), 256, 0, stream>>>(fq, w2z, sf, wsum + 5, invF, x1, d_out, 2048, 2048, 8192, flag);
}

// Round 5
// 1025.360 us; speedup vs baseline: 4.0907x; 4.0907x over previous
//
#include <hip/hip_runtime.h>
#include <hip/hip_bf16.h>
#include <stdint.h>

typedef __bf16 bf16;
typedef __bf16 v8bf __attribute__((ext_vector_type(8)));
typedef float  v4f  __attribute__((ext_vector_type(4)));

#define MFMA_BF16(a,b,c) __builtin_amdgcn_mfma_f32_16x16x32_bf16((a),(b),(c),0,0,0)

__device__ __forceinline__ void glds16(const bf16* g, bf16* l) {
  __builtin_amdgcn_global_load_lds(
      (const __attribute__((address_space(1))) void*)g,
      (__attribute__((address_space(3))) void*)l, 16, 0, 0);
}

__device__ __forceinline__ float wred_sum(float v) {
#pragma unroll
  for (int o = 32; o; o >>= 1) v += __shfl_xor(v, o);
  return v;
}
__device__ __forceinline__ float wred_max(float v) {
#pragma unroll
  for (int o = 32; o; o >>= 1) v = fmaxf(v, __shfl_xor(v, o));
  return v;
}

// ---------------- dtype sniffer (inputs turned out fp32; keep robust) ----------------
__global__ void k_sniff(const unsigned short* __restrict__ x, int* __restrict__ flag) {
  int cnt = 0;
  for (int i = threadIdx.x; i < 2048; i += 64) {
    const unsigned short u = x[i];
    const int e = (u >> 7) & 0xFF;
    if (u == 0 || (e >= 100 && e <= 140)) cnt++;
  }
#pragma unroll
  for (int o = 32; o; o >>= 1) cnt += __shfl_xor(cnt, o);
  if (threadIdx.x == 0) flag[0] = (cnt >= 1844) ? 0 : 1;  // 0 = bf16, 1 = f32
}

// ---------------- small utility kernels ----------------

__global__ void k_zero(float* p, int n) {
  int i = threadIdx.x;
  if (i < n) p[i] = 0.0f;
}

__global__ __launch_bounds__(256) void k_abssum(const void* __restrict__ w, int n,
                                                const int* __restrict__ flag,
                                                float* __restrict__ out) {
  const int tid = threadIdx.x;
  const int f32 = flag[0];
  __shared__ float sred[4];
  float s = 0.0f;
  if (f32) {
    const float4* p = (const float4*)w;
    for (int i = (blockIdx.x * 256 + tid) * 2; i * 4 < n; i += gridDim.x * 512) {
      float4 a = p[i], b = p[i + 1];
      s += fabsf(a.x) + fabsf(a.y) + fabsf(a.z) + fabsf(a.w) +
           fabsf(b.x) + fabsf(b.y) + fabsf(b.z) + fabsf(b.w);
    }
  } else {
    const bf16* p = (const bf16*)w;
    for (int i = (blockIdx.x * 256 + tid) * 8; i < n; i += gridDim.x * 2048) {
      v8bf v = *(const v8bf*)(p + i);
#pragma unroll
      for (int j = 0; j < 8; j++) s += fabsf((float)v[j]);
    }
  }
  s = wred_sum(s);
  if ((tid & 63) == 0) sred[tid >> 6] = s;
  __syncthreads();
  if (tid == 0) atomicAdd(out, sred[0] + sred[1] + sred[2] + sred[3]);
}

__global__ __launch_bounds__(256) void k_wquant(const void* __restrict__ w, bf16* __restrict__ o,
                                                const float* __restrict__ sum, float invn,
                                                const int* __restrict__ flag) {
  const int gid = blockIdx.x * 256 + threadIdx.x;
  const int i = gid * 8;
  const float ws = 1.0f / fmaxf(sum[0] * invn, 1e-5f);
  const int f32 = flag[0];
  float v[8];
  if (f32) {
    float4 a = ((const float4*)w)[gid * 2];
    float4 b = ((const float4*)w)[gid * 2 + 1];
    v[0] = a.x; v[1] = a.y; v[2] = a.z; v[3] = a.w;
    v[4] = b.x; v[5] = b.y; v[6] = b.z; v[7] = b.w;
  } else {
    v8bf t = *(const v8bf*)((const bf16*)w + i);
#pragma unroll
    for (int j = 0; j < 8; j++) v[j] = (float)t[j];
  }
  v8bf r;
#pragma unroll
  for (int j = 0; j < 8; j++) {
    float t = rintf(v[j] * ws);
    r[j] = (bf16)fminf(fmaxf(t, -1.0f), 1.0f);
  }
  *(v8bf*)(o + i) = r;
}

// LayerNorm + per-row absmax quantize (integer-valued bf16 out).
template <bool XINT>
__global__ __launch_bounds__(256) void k_lnq(const void* __restrict__ x, const void* __restrict__ g,
                                             const void* __restrict__ b, bf16* __restrict__ q,
                                             float* __restrict__ sc, const int* __restrict__ flag) {
  const int row = blockIdx.x, tid = threadIdx.x;
  const int f32 = flag[0];
  __shared__ float sred[4];
  float v[8];
#pragma unroll
  for (int i = 0; i < 8; i++) {
    const size_t idx = (size_t)row * 2048 + tid + 256 * i;
    if (XINT)      v[i] = ((const float*)x)[idx];
    else if (f32)  v[i] = ((const float*)x)[idx];
    else           v[i] = (float)((const bf16*)x)[idx];
  }
  float s = 0.0f;
#pragma unroll
  for (int i = 0; i < 8; i++) s += v[i];
  s = wred_sum(s);
  if ((tid & 63) == 0) sred[tid >> 6] = s;
  __syncthreads();
  const float mean = (sred[0] + sred[1] + sred[2] + sred[3]) * (1.0f / 2048.0f);
  __syncthreads();
  float vs = 0.0f;
#pragma unroll
  for (int i = 0; i < 8; i++) { float d = v[i] - mean; vs += d * d; }
  vs = wred_sum(vs);
  if ((tid & 63) == 0) sred[tid >> 6] = vs;
  __syncthreads();
  const float rstd = rsqrtf((sred[0] + sred[1] + sred[2] + sred[3]) * (1.0f / 2048.0f) + 1e-6f);
  __syncthreads();
  float hq[8];
  float am = 0.0f;
#pragma unroll
  for (int i = 0; i < 8; i++) {
    const int c = tid + 256 * i;
    const float gv = f32 ? ((const float*)g)[c] : (float)((const bf16*)g)[c];
    const float bv = f32 ? ((const float*)b)[c] : (float)((const bf16*)b)[c];
    hq[i] = (v[i] - mean) * rstd * gv + bv;
    am = fmaxf(am, fabsf(hq[i]));
  }
  am = wred_max(am);
  if ((tid & 63) == 0) sred[tid >> 6] = am;
  __syncthreads();
  am = fmaxf(fmaxf(sred[0], sred[1]), fmaxf(sred[2], sred[3]));
  const float cl = fmaxf(am, 1e-5f);
  const float s127 = 127.0f / cl;
#pragma unroll
  for (int i = 0; i < 8; i++) {
    float r = rintf(hq[i] * s127);
    r = fminf(fmaxf(r, -128.0f), 127.0f);
    q[(size_t)row * 2048 + tid + 256 * i] = (bf16)r;
  }
  if (tid == 0) sc[row] = cl * (1.0f / 127.0f);
}

// plain per-row absmax quantize; safe in-place
template <int IT>
__global__ __launch_bounds__(256) void k_rowq(const bf16* __restrict__ in, bf16* __restrict__ q,
                                              float* __restrict__ sc) {
  const int row = blockIdx.x, tid = threadIdx.x;
  const int C = IT * 256;
  __shared__ float sred[4];
  const bf16* xr = in + (size_t)row * C;
  float v[IT];
  float am = 0.0f;
#pragma unroll
  for (int i = 0; i < IT; i++) {
    v[i] = (float)xr[tid + 256 * i];
    am = fmaxf(am, fabsf(v[i]));
  }
  am = wred_max(am);
  if ((tid & 63) == 0) sred[tid >> 6] = am;
  __syncthreads();
  am = fmaxf(fmaxf(sred[0], sred[1]), fmaxf(sred[2], sred[3]));
  const float cl = fmaxf(am, 1e-5f);
  const float s127 = 127.0f / cl;
#pragma unroll
  for (int i = 0; i < IT; i++) {
    float r = rintf(v[i] * s127);
    r = fminf(fmaxf(r, -128.0f), 127.0f);
    q[(size_t)row * C + tid + 256 * i] = (bf16)r;
  }
  if (tid == 0) sc[row] = cl * (1.0f / 127.0f);
}

// transpose V (2048 x 512) -> Vt (512 x 2048)
__global__ __launch_bounds__(256) void k_vt(const bf16* __restrict__ V, bf16* __restrict__ Vt) {
  const int gid = blockIdx.x * 256 + threadIdx.x;
  const int d = gid >> 8;          // 0..511
  const int t0 = (gid & 255) * 8;  // 0..2040
  v8bf v;
#pragma unroll
  for (int i = 0; i < 8; i++) v[i] = V[(size_t)(t0 + i) * 512 + d];
  *(v8bf*)(Vt + (size_t)d * 2048 + t0) = v;
}

// ---------------- GEMM (m97 structure: global_load_lds width-16 staging) ----------------
// C[t,n] = sA[t]*cw * sum_k A[t,k]*B[n,k];  A,B internal bf16 (integer-valued).
// EPI 0: out bf16 = val                        (QKV projections)
// EPI 1: out f32  = resid(ext, per flag) + val (wo projection -> x1)
// EPI 2: out bf16 = relu(val)^2                (w1 -> F)
// EPI 3: out(ext, per flag) = f32 resid + val  (w2 -> final output)
template <int EPI>
__global__ __launch_bounds__(256) void k_gemm(const bf16* __restrict__ A, const bf16* __restrict__ B,
                                              const float* __restrict__ sA,
                                              const float* __restrict__ wsum, float winv,
                                              const void* __restrict__ resid, void* __restrict__ out,
                                              int M, int N, int K, const int* __restrict__ flag) {
  __shared__ __align__(16) bf16 As[128 * 32];
  __shared__ __align__(16) bf16 Bs[128 * 32];
  const int tid = threadIdx.x;
  const int lane = tid & 63;
  const int ml = lane & 15;
  const int q4 = lane >> 4;
  const int wid = tid >> 6;
  const int wM = wid >> 1;
  const int wN = wid & 1;
  const int m0 = blockIdx.y * 128;
  const int n0 = blockIdx.x * 128;

  const int r0 = tid >> 2;          // 0..63
  const int c0 = (tid & 3) * 8;     // 0,8,16,24
  const bf16* Ag0 = A + (size_t)(m0 + r0) * K + c0;
  const bf16* Ag1 = Ag0 + (size_t)64 * K;
  const bf16* Bg0 = B + (size_t)(n0 + r0) * K + c0;
  const bf16* Bg1 = Bg0 + (size_t)64 * K;
  // lane l of wave w writes LDS at base + l*16B == &As[(w*64+l)*8] == As[tid*8]
  bf16* as0 = &As[wid * 512];
  bf16* as1 = &As[2048 + wid * 512];
  bf16* bs0 = &Bs[wid * 512];
  bf16* bs1 = &Bs[2048 + wid * 512];

  v4f acc[4][4] = {};

  for (int k0 = 0; k0 < K; k0 += 32) {
    __syncthreads();  // prior iteration's readers done before overwrite
    glds16(Ag0 + k0, as0);
    glds16(Ag1 + k0, as1);
    glds16(Bg0 + k0, bs0);
    glds16(Bg1 + k0, bs1);
    __syncthreads();  // staging complete (barrier drains vmcnt)
    v8bf af[4], bfr[4];
#pragma unroll
    for (int i = 0; i < 4; i++) af[i] = *(const v8bf*)&As[(wM * 64 + i * 16 + ml) * 32 + q4 * 8];
#pragma unroll
    for (int j = 0; j < 4; j++) bfr[j] = *(const v8bf*)&Bs[(wN * 64 + j * 16 + ml) * 32 + q4 * 8];
#pragma unroll
    for (int i = 0; i < 4; i++)
#pragma unroll
      for (int j = 0; j < 4; j++) acc[i][j] = MFMA_BF16(af[i], bfr[j], acc[i][j]);
  }

  const float cw = fmaxf(wsum[0] * winv, 1e-5f);
  const int f32 = flag[0];
#pragma unroll
  for (int i = 0; i < 4; i++) {
#pragma unroll
    for (int r = 0; r < 4; r++) {
      const int row = m0 + wM * 64 + i * 16 + q4 * 4 + r;
      const float sa = sA[row] * cw;
#pragma unroll
      for (int j = 0; j < 4; j++) {
        const int col = n0 + wN * 64 + j * 16 + ml;
        const float val = acc[i][j][r] * sa;
        const size_t idx = (size_t)row * N + col;
        if (EPI == 0) {
          ((bf16*)out)[idx] = (bf16)val;
        } else if (EPI == 1) {
          const float rv = f32 ? ((const float*)resid)[idx] : (float)((const bf16*)resid)[idx];
          ((float*)out)[idx] = rv + val;
        } else if (EPI == 2) {
          float u = fmaxf(val, 0.0f);
          ((bf16*)out)[idx] = (bf16)(u * u);
        } else {
          const float ov = ((const float*)resid)[idx] + val;
          if (f32) ((float*)out)[idx] = ov;
          else     ((bf16*)out)[idx] = (bf16)ov;
        }
      }
    }
  }
}

// ---------------- MFMA flash attention (causal, GQA 32q/8kv heads, D=64) ----------------
// 1 wave per 16 queries; K-frags & V^T-frags straight from global (L2-resident);
// P round-trips through per-wave padded LDS; online softmax over 16-lane groups.
__global__ __launch_bounds__(256) void k_attn(const bf16* __restrict__ Q, const bf16* __restrict__ Kb,
                                              const bf16* __restrict__ Vt, bf16* __restrict__ O) {
  const int qb = blockIdx.x;
  const int h = blockIdx.y;
  const int kvh = h >> 2;
  const int tid = threadIdx.x;
  const int wid = tid >> 6, lane = tid & 63;
  const int ml = lane & 15, q4 = lane >> 4;
  const int qw0 = qb * 64 + wid * 16;

  __shared__ __align__(16) bf16 Pl[4][16][40];  // per-wave P tile, stride-40 padded

  v8bf qf0, qf1;
  {
    const bf16* qr = Q + (size_t)(qw0 + ml) * 2048 + h * 64 + q4 * 8;
    qf0 = *(const v8bf*)qr;
    qf1 = *(const v8bf*)(qr + 32);
  }

  float m[4], l[4];
  v4f accO[4] = {};
#pragma unroll
  for (int r = 0; r < 4; r++) { m[r] = -1e30f; l[r] = 0.0f; }

  const int kend = qw0 + 16;
  for (int kb = 0; kb < kend; kb += 32) {
    v4f s0 = {0.0f, 0.0f, 0.0f, 0.0f}, s1 = {0.0f, 0.0f, 0.0f, 0.0f};
    {
      const bf16* kp = Kb + (size_t)(kb + ml) * 512 + kvh * 64 + q4 * 8;
      v8bf ka = *(const v8bf*)kp;
      v8bf kc = *(const v8bf*)(kp + 32);
      s0 = MFMA_BF16(qf0, ka, s0);
      s0 = MFMA_BF16(qf1, kc, s0);
      const bf16* kp2 = kp + 16 * 512;
      v8bf kd = *(const v8bf*)kp2;
      v8bf ke = *(const v8bf*)(kp2 + 32);
      s1 = MFMA_BF16(qf0, kd, s1);
      s1 = MFMA_BF16(qf1, ke, s1);
    }
    float p0[4], p1[4], rm[4];
#pragma unroll
    for (int r = 0; r < 4; r++) {
      const int qg = qw0 + q4 * 4 + r;
      p0[r] = (kb + ml <= qg) ? s0[r] * 0.125f : -1e30f;
      p1[r] = (kb + 16 + ml <= qg) ? s1[r] * 0.125f : -1e30f;
      rm[r] = fmaxf(p0[r], p1[r]);
    }
#pragma unroll
    for (int off = 1; off <= 8; off <<= 1)
#pragma unroll
      for (int r = 0; r < 4; r++) rm[r] = fmaxf(rm[r], __shfl_xor(rm[r], off));
    float alpha[4], rs[4];
#pragma unroll
    for (int r = 0; r < 4; r++) {
      const float mn = fmaxf(m[r], rm[r]);
      alpha[r] = __expf(m[r] - mn);
      m[r] = mn;
      const bf16 e0 = (bf16)__expf(p0[r] - mn);
      const bf16 e1 = (bf16)__expf(p1[r] - mn);
      Pl[wid][q4 * 4 + r][ml] = e0;
      Pl[wid][q4 * 4 + r][16 + ml] = e1;
      rs[r] = (float)e0 + (float)e1;
    }
#pragma unroll
    for (int off = 1; off <= 8; off <<= 1)
#pragma unroll
      for (int r = 0; r < 4; r++) rs[r] += __shfl_xor(rs[r], off);
#pragma unroll
    for (int r = 0; r < 4; r++) l[r] = l[r] * alpha[r] + rs[r];
#pragma unroll
    for (int d = 0; d < 4; d++)
#pragma unroll
      for (int r = 0; r < 4; r++) accO[d][r] *= alpha[r];
    // same-wave LDS RAW: drain ds queue; clobber pins ordering at source level
    asm volatile("s_waitcnt lgkmcnt(0)" ::: "memory");
    const v8bf pf = *(const v8bf*)&Pl[wid][ml][q4 * 8];
    const bf16* vp = Vt + (size_t)(kvh * 64 + ml) * 2048 + kb + q4 * 8;
#pragma unroll
    for (int d = 0; d < 4; d++) {
      const v8bf vf = *(const v8bf*)(vp + (size_t)d * 16 * 2048);
      accO[d] = MFMA_BF16(pf, vf, accO[d]);
    }
  }

#pragma unroll
  for (int d = 0; d < 4; d++)
#pragma unroll
    for (int r = 0; r < 4; r++) {
      const int qg = qw0 + q4 * 4 + r;
      O[(size_t)qg * 2048 + h * 64 + d * 16 + ml] = (bf16)(accO[d][r] / l[r]);
    }
}

// ---------------- launcher ----------------
// Workspace (96 MB + 64 KB):
//   scalars: wsum[8]@0, s1@8K, so@16K, s2@24K, sf@32K, flag@40K
//   R0 [ 0,32)MB: w1z ............. then w2z (quant AFTER gemm<2>)
//   R1 [32,64)MB: wqz+0 wkz+8 wvz+10 woz+12, then Fb/fq (in-place rowq)
//   R2 [64,80)MB: Qb+0 Kbuf+8 Vb+10 Vt+12, then x1 (fp32, after attention)
//   R3 [80,88)MB: xq1 -> oq -> xq2
//   R4 [88,96)MB: Ob
extern "C" void kernel_launch(void* const* d_in, const int* in_sizes, int n_in, void* d_out,
                              int out_size, void* d_ws, size_t ws_size, hipStream_t stream) {
  const void* x = d_in[0];
  const void* g1 = d_in[1];
  const void* b1 = d_in[2];
  const void* g2 = d_in[3];
  const void* b2 = d_in[4];
  const void* wq = d_in[5];
  const void* wk = d_in[6];
  const void* wv = d_in[7];
  const void* wo = d_in[8];
  const void* w1 = d_in[9];
  const void* w2 = d_in[10];

  char* ws = (char*)d_ws;
  const size_t MB = 1ull << 20;
  float* wsum = (float*)ws;
  float* s1 = (float*)(ws + 8192);
  float* so = (float*)(ws + 16384);
  float* s2 = (float*)(ws + 24576);
  float* sf = (float*)(ws + 32768);
  int* flag = (int*)(ws + 40960);
  char* big = ws + 65536;

  bf16* w1z = (bf16*)(big);
  bf16* w2z = (bf16*)(big);
  bf16* wqz = (bf16*)(big + 32 * MB);
  bf16* wkz = (bf16*)(big + 40 * MB);
  bf16* wvz = (bf16*)(big + 42 * MB);
  bf16* woz = (bf16*)(big + 44 * MB);
  bf16* Fb  = (bf16*)(big + 32 * MB);
  bf16* fq  = Fb;
  bf16* Qb   = (bf16*)(big + 64 * MB);
  bf16* Kbuf = (bf16*)(big + 72 * MB);
  bf16* Vb   = (bf16*)(big + 74 * MB);
  bf16* Vt   = (bf16*)(big + 76 * MB);
  float* x1  = (float*)(big + 64 * MB);
  bf16* xq1 = (bf16*)(big + 80 * MB);
  bf16* oq  = xq1;
  bf16* xq2 = xq1;
  bf16* Ob  = (bf16*)(big + 88 * MB);

  const float invD2 = 1.0f / 4194304.0f;
  const float invKV = 1.0f / 1048576.0f;
  const float invF = 1.0f / 16777216.0f;

  k_sniff<<<1, 64, 0, stream>>>((const unsigned short*)x, flag);
  k_zero<<<1, 64, 0, stream>>>(wsum, 8);
  k_abssum<<<512, 256, 0, stream>>>(wq, 2048 * 2048, flag, wsum + 0);
  k_abssum<<<512, 256, 0, stream>>>(wk, 512 * 2048, flag, wsum + 1);
  k_abssum<<<512, 256, 0, stream>>>(wv, 512 * 2048, flag, wsum + 2);
  k_abssum<<<512, 256, 0, stream>>>(wo, 2048 * 2048, flag, wsum + 3);
  k_abssum<<<512, 256, 0, stream>>>(w1, 8192 * 2048, flag, wsum + 4);
  k_abssum<<<512, 256, 0, stream>>>(w2, 2048 * 8192, flag, wsum + 5);
  k_wquant<<<2048, 256, 0, stream>>>(wq, wqz, wsum + 0, invD2, flag);
  k_wquant<<<512, 256, 0, stream>>>(wk, wkz, wsum + 1, invKV, flag);
  k_wquant<<<512, 256, 0, stream>>>(wv, wvz, wsum + 2, invKV, flag);
  k_wquant<<<2048, 256, 0, stream>>>(wo, woz, wsum + 3, invD2, flag);
  k_wquant<<<8192, 256, 0, stream>>>(w1, w1z, wsum + 4, invF, flag);

  // attention sublayer
  k_lnq<false><<<2048, 256, 0, stream>>>(x, g1, b1, xq1, s1, flag);
  k_gemm<0><<<dim3(16, 16), 256, 0, stream>>>(xq1, wqz, s1, wsum + 0, invD2, nullptr, Qb, 2048, 2048, 2048, flag);
  k_gemm<0><<<dim3(4, 16), 256, 0, stream>>>(xq1, wkz, s1, wsum + 1, invKV, nullptr, Kbuf, 2048, 512, 2048, flag);
  k_gemm<0><<<dim3(4, 16), 256, 0, stream>>>(xq1, wvz, s1, wsum + 2, invKV, nullptr, Vb, 2048, 512, 2048, flag);
  k_vt<<<512, 256, 0, stream>>>(Vb, Vt);
  k_attn<<<dim3(32, 32), 256, 0, stream>>>(Qb, Kbuf, Vt, Ob);
  k_rowq<8><<<2048, 256, 0, stream>>>(Ob, oq, so);
  k_gemm<1><<<dim3(16, 16), 256, 0, stream>>>(oq, woz, so, wsum + 3, invD2, x, x1, 2048, 2048, 2048, flag);

  // FFN sublayer
  k_lnq<true><<<2048, 256, 0, stream>>>(x1, g2, b2, xq2, s2, flag);
  k_gemm<2><<<dim3(64, 16), 256, 0, stream>>>(xq2, w1z, s2, wsum + 4, invF, nullptr, Fb, 2048, 8192, 2048, flag);
  k_wquant<<<8192, 256, 0, stream>>>(w2, w2z, wsum + 5, invF, flag);
  k_rowq<32><<<2048, 256, 0, stream>>>(Fb, fq, sf);
  k_gemm<3><<<dim3(16, 16), 256, 0, stream>>>(fq, w2z, sf, wsum + 5, invF, x1, d_out, 2048, 2048, 8192, flag);
}